// Round 7
// baseline (254.540 us; speedup 1.0000x reference)
//
#include <hip/hip_runtime.h>

#define NNODES 100000
#define NEDGES 1600000
#define DD 128
#define BM 32
#define NBUCK 98                 // coarse buckets of 1024 nodes
#define NBLK_MLP (NNODES / BM)   // 3125 exactly (100000 = 3125*32)
#define CAP 32                   // bin1 LDS staging entries per bucket
#define CAPB 20480               // ebuf capacity per bucket (mean 16327)
#define BIN1_WGS 200
#define BIN1_EPW 8192            // edges per workgroup (8 rounds x 1024)

// ---------------- workspace layout (ints) ----------------
// [0,100000): weight tables (ushort view)
// [100000,100098): gcur | [100128,100226): bbase
// [100352,200353): offs | [201216,1801216): esrc
#define WS_GCUR 100000
#define WS_BBASE 100128
#define WS_OFFS 100352
#define WS_ESRC 201216

// ushort offsets inside the weight-table region (tile-packed)
#define WT1HI 0        // K=256: 8 c16 x 8 kk tiles, 1KB/tile
#define WT1LO 32768
#define WT2HI 65536    // K=128: 8 x 4 tiles
#define WT2LO 81920
#define WT3HI 98304
#define WT3LO 114688

typedef __attribute__((ext_vector_type(8))) short short8;  // 8 bf16
typedef __attribute__((ext_vector_type(4))) float f32x4;

// x ~= hi + lo, both bf16 (RNE). hi*whi + hi*wlo + lo*whi gives ~2^-16 rel err.
__device__ __forceinline__ void bf16_split(float x, ushort& hi, ushort& lo) {
  unsigned u = __float_as_uint(x);
  ushort h = (ushort)((u + 0x7FFFu + ((u >> 16) & 1u)) >> 16);
  float r = x - __uint_as_float(((unsigned)h) << 16);  // exact in fp32
  unsigned v = __float_as_uint(r);
  ushort l = (ushort)((v + 0x7FFFu + ((v >> 16) & 1u)) >> 16);
  hi = h;
  lo = l;
}

__device__ __forceinline__ void split8(const float4 v0, const float4 v1,
                                       short8& hi, short8& lo) {
  float x[8] = {v0.x, v0.y, v0.z, v0.w, v1.x, v1.y, v1.z, v1.w};
#pragma unroll
  for (int j = 0; j < 8; ++j) {
    ushort h, l;
    bf16_split(x[j], h, l);
    hi[j] = (short)h;
    lo[j] = (short)l;
  }
}

// ---------------- bin1: coarse-bucket scatter, LDS line-coalesced flush -------
__global__ __launch_bounds__(256) void bin1_kernel(const int* __restrict__ src,
                                                   const int* __restrict__ dst,
                                                   int* __restrict__ gcur,
                                                   unsigned* __restrict__ ebuf) {
  __shared__ unsigned stage[NBUCK][CAP];
  __shared__ int scnt[NBUCK];
  const int t = threadIdx.x;
  for (int i = t; i < NBUCK; i += 256) scnt[i] = 0;
  __syncthreads();
  const int e0 = blockIdx.x * BIN1_EPW;
  for (int r = 0; r < BIN1_EPW / 1024; ++r) {
    unsigned item[4];
    int buck[4];
    int pend[4];
#pragma unroll
    for (int j = 0; j < 4; ++j) {
      pend[j] = 0;
      int e = e0 + r * 1024 + j * 256 + t;
      if (e < NEDGES) {
        int d = dst[e];
        int s = src[e];
        buck[j] = d >> 10;
        item[j] = ((unsigned)(d & 1023) << 17) | (unsigned)s;
        int p = atomicAdd(&scnt[buck[j]], 1);
        if (p < CAP)
          stage[buck[j]][p] = item[j];
        else
          pend[j] = 1;
      }
    }
    int pendLeft;
    do {
      __syncthreads();
      if (t < NBUCK && scnt[t] >= CAP) {
        int base = t * CAPB + atomicAdd(&gcur[t], CAP);
        for (int q = 0; q < CAP; ++q) ebuf[base + q] = stage[t][q];
        scnt[t] = 0;
      }
      __syncthreads();
      int mypend = 0;
#pragma unroll
      for (int j = 0; j < 4; ++j) {
        if (pend[j]) {
          int p = atomicAdd(&scnt[buck[j]], 1);
          if (p < CAP) {
            stage[buck[j]][p] = item[j];
            pend[j] = 0;
          } else {
            mypend = 1;
          }
        }
      }
      pendLeft = __syncthreads_count(mypend);
    } while (pendLeft > 0);
  }
  __syncthreads();
  if (t < NBUCK) {
    int n = scnt[t];
    if (n > 0) {
      int base = t * CAPB + atomicAdd(&gcur[t], n);
      for (int q = 0; q < n; ++q) ebuf[base + q] = stage[t][q];
    }
  }
}

// ---------------- bscan: exclusive scan of 98 bucket counts ------------------
__global__ __launch_bounds__(128) void bscan_kernel(const int* __restrict__ gcur,
                                                    int* __restrict__ bbase,
                                                    int* __restrict__ offs) {
  __shared__ int s[128];
  const int t = threadIdx.x;
  int v = (t < NBUCK) ? gcur[t] : 0;
  s[t] = v;
  __syncthreads();
  for (int off = 1; off < 128; off <<= 1) {
    int u = (t >= off) ? s[t - off] : 0;
    __syncthreads();
    s[t] += u;
    __syncthreads();
  }
  if (t < NBUCK) bbase[t] = s[t] - v;
  if (t == NBUCK - 1) offs[NNODES] = s[t];
}

// ---------------- bucket_csr: LDS hist + scan + scatter ----------------------
__global__ __launch_bounds__(1024) void bucket_csr_kernel(const unsigned* __restrict__ ebuf,
                                                          const int* __restrict__ gcur,
                                                          const int* __restrict__ bbase,
                                                          int* __restrict__ offs,
                                                          int* __restrict__ esrc) {
  __shared__ int h[1024];
  __shared__ int cur[1024];
  const int t = threadIdx.x;
  const int c = blockIdx.x;
  const int n = gcur[c];
  const unsigned* eb = ebuf + c * CAPB;
  h[t] = 0;
  __syncthreads();
  for (int i = t; i < n; i += 1024) atomicAdd(&h[eb[i] >> 17], 1);
  __syncthreads();
  int v = h[t];
  for (int off = 1; off < 1024; off <<= 1) {
    int u = (t >= off) ? h[t - off] : 0;
    __syncthreads();
    h[t] += u;
    __syncthreads();
  }
  int excl = h[t] - v + bbase[c];
  int node = (c << 10) + t;
  if (node < NNODES) offs[node] = excl;
  cur[t] = excl;
  __syncthreads();
  for (int i = t; i < n; i += 1024) {
    unsigned e = eb[i];
    int p = atomicAdd(&cur[e >> 17], 1);
    esrc[p] = (int)(e & 0x1FFFFu);
  }
}

// ---------------- weight prep: fp32 -> split-bf16, tile-packed ----------------
__global__ __launch_bounds__(256) void wprep_kernel(const float* __restrict__ W1,
                                                    const float* __restrict__ W2,
                                                    const float* __restrict__ W3,
                                                    ushort* __restrict__ wt) {
  int tid = blockIdx.x * 256 + threadIdx.x;  // 65536 total
  const float* W;
  int dstHi, dstLo, k, col;
  if (tid < 32768) {  // layer 1, K=256: tiles = c16*8 + kk
    int j = tid & 7, l = (tid >> 3) & 63, tile = tid >> 9;
    int kk = tile & 7, c16 = tile >> 3;
    k = kk * 32 + (l >> 4) * 8 + j;
    col = c16 * 16 + (l & 15);
    W = W1;
    dstHi = WT1HI + tid;
    dstLo = WT1LO + tid;
  } else {  // layers 2/3, K=128: tiles = c16*4 + kk
    int t2 = tid - 32768;
    int which = t2 >> 14;
    int t1 = t2 & 16383;
    int j = t1 & 7, l = (t1 >> 3) & 63, tile = t1 >> 9;
    int kk = tile & 3, c16 = tile >> 2;
    k = kk * 32 + (l >> 4) * 8 + j;
    col = c16 * 16 + (l & 15);
    W = which ? W3 : W2;
    dstHi = (which ? WT3HI : WT2HI) + t1;
    dstLo = (which ? WT3LO : WT2LO) + t1;
  }
  ushort hi, lo;
  bf16_split(W[k * DD + col], hi, lo);
  wt[dstHi] = hi;
  wt[dstLo] = lo;
}

// ---------------- fused gather + MFMA MLP (BM=32, 16KB LDS) ----------------
// Frag maps (verified): A: lane l = A[row=l&15][k=(l>>4)*8+j];
// B: lane l = B[k=(l>>4)*8+j][col=l&15]; D: lane l reg i = [(l>>4)*4+i][l&15].
// Block = 32 rows x 128 cols, 4 waves. Wave w: rows (w&1)*16, cols (w>>1)*64.
// acc[4] = 4 col-tiles of 16x16.

// 4 k-steps from swizzled LDS ([32][128] ushort, 256B row stride).
// KT = k-tile count of the weight table, tileOff = starting k-tile.
template <int KT>
__device__ __forceinline__ void lds_ksteps(const ushort* Hh, const ushort* Hl,
                                           const ushort* __restrict__ WhiT,
                                           const ushort* __restrict__ WloT,
                                           int tileOff, int rb, int wc, int lane,
                                           int l15, int lhi, f32x4 acc[4]) {
#pragma unroll 2
  for (int kk = 0; kk < 4; ++kk) {
    int row = rb + l15;
    int byte = (row * 256 + kk * 64 + lhi * 16) ^ ((row & 7) << 4);
    short8 ahi = *(const short8*)((const char*)Hh + byte);
    short8 alo = *(const short8*)((const char*)Hl + byte);
#pragma unroll
    for (int ct = 0; ct < 4; ++ct) {
      int tb = ((wc * 4 + ct) * KT + tileOff + kk) * 512 + lane * 8;
      short8 bhi = *(const short8*)&WhiT[tb];
      short8 blo = *(const short8*)&WloT[tb];
      acc[ct] = __builtin_amdgcn_mfma_f32_16x16x32_bf16(ahi, bhi, acc[ct], 0, 0, 0);
      acc[ct] = __builtin_amdgcn_mfma_f32_16x16x32_bf16(ahi, blo, acc[ct], 0, 0, 0);
      acc[ct] = __builtin_amdgcn_mfma_f32_16x16x32_bf16(alo, bhi, acc[ct], 0, 0, 0);
    }
  }
}

// one 32-k step with A from global memory (nf half of layer 1)
__device__ __forceinline__ void l1_step(const float* __restrict__ srcb,
                                        const ushort* __restrict__ wt,
                                        int kkTile, int kOff, int rowA,
                                        int wc, int lane, int lhi,
                                        f32x4 acc[4]) {
  const float* p = srcb + rowA * DD + kOff + lhi * 8;
  float4 v0 = *(const float4*)p;
  float4 v1 = *(const float4*)(p + 4);
  short8 ahi, alo;
  split8(v0, v1, ahi, alo);
#pragma unroll
  for (int ct = 0; ct < 4; ++ct) {
    int tb = ((wc * 4 + ct) * 8 + kkTile) * 512 + lane * 8;
    short8 bhi = *(const short8*)&wt[WT1HI + tb];
    short8 blo = *(const short8*)&wt[WT1LO + tb];
    acc[ct] = __builtin_amdgcn_mfma_f32_16x16x32_bf16(ahi, bhi, acc[ct], 0, 0, 0);
    acc[ct] = __builtin_amdgcn_mfma_f32_16x16x32_bf16(ahi, blo, acc[ct], 0, 0, 0);
    acc[ct] = __builtin_amdgcn_mfma_f32_16x16x32_bf16(alo, bhi, acc[ct], 0, 0, 0);
  }
}

// bias + ReLU + split-bf16 + swizzled LDS store
__device__ __forceinline__ void store_h(ushort* Hh, ushort* Hl,
                                        const float* __restrict__ b,
                                        int rb, int wc, int l15, int lhi,
                                        f32x4 acc[4]) {
#pragma unroll
  for (int ct = 0; ct < 4; ++ct) {
    int col = wc * 64 + ct * 16 + l15;
    float bias = b[col];
#pragma unroll
    for (int i = 0; i < 4; ++i) {
      int row = rb + lhi * 4 + i;
      float v = fmaxf(acc[ct][i] + bias, 0.f);
      ushort h, l;
      bf16_split(v, h, l);
      int byte = (row * 256 + col * 2) ^ ((row & 7) << 4);
      *(ushort*)((char*)Hh + byte) = h;
      *(ushort*)((char*)Hl + byte) = l;
    }
  }
}

__global__ __launch_bounds__(256, 6) void fused_kernel(const float* __restrict__ nf,
                                                       const int* __restrict__ offs,
                                                       const int* __restrict__ esrc,
                                                       const ushort* __restrict__ wt,
                                                       const float* __restrict__ b1,
                                                       const float* __restrict__ b2,
                                                       const float* __restrict__ b3,
                                                       float* __restrict__ out) {
  // X (agg, split-bf16, swizzled) [32][128] hi/lo = 16KB.
  // H1 and H2 reuse the same region (barrier-separated).
  __shared__ ushort smem[8192];
  ushort* Xhi = smem;
  ushort* Xlo = smem + 4096;

  const int t = threadIdx.x;
  const int lane = t & 63;
  const int w = t >> 6;
  const int rb = (w & 1) * 16;   // wave row base within block
  const int wc = w >> 1;         // wave 64-col half
  const int l15 = lane & 15;
  const int lhi = lane >> 4;
  const int base = blockIdx.x * BM;  // exact: 100000 = 3125*32

  // ---- phase 1: gather-aggregate this block's 32 nodes into X ----
  {
    const int g = t >> 5;        // 8 groups of 32 lanes
    const int l32 = t & 31;
    const int col = l32 << 2;    // 4 floats per lane
    for (int j = 0; j < 4; ++j) {
      const int r = g * 4 + j;   // block-local row
      const int node = base + r;
      float4 a0 = make_float4(0.f, 0.f, 0.f, 0.f);
      float4 a1 = make_float4(0.f, 0.f, 0.f, 0.f);
      float4 a2 = make_float4(0.f, 0.f, 0.f, 0.f);
      float4 a3 = make_float4(0.f, 0.f, 0.f, 0.f);
      const int beg = offs[node];
      const int end = offs[node + 1];
      int i = beg;
      for (; i + 3 < end; i += 4) {
        int s0 = esrc[i];
        int s1 = esrc[i + 1];
        int s2 = esrc[i + 2];
        int s3 = esrc[i + 3];
        float4 v0 = *(const float4*)&nf[s0 * DD + col];
        float4 v1 = *(const float4*)&nf[s1 * DD + col];
        float4 v2 = *(const float4*)&nf[s2 * DD + col];
        float4 v3 = *(const float4*)&nf[s3 * DD + col];
        a0.x += v0.x; a0.y += v0.y; a0.z += v0.z; a0.w += v0.w;
        a1.x += v1.x; a1.y += v1.y; a1.z += v1.z; a1.w += v1.w;
        a2.x += v2.x; a2.y += v2.y; a2.z += v2.z; a2.w += v2.w;
        a3.x += v3.x; a3.y += v3.y; a3.z += v3.z; a3.w += v3.w;
      }
      for (; i < end; ++i) {
        int s0 = esrc[i];
        float4 v0 = *(const float4*)&nf[s0 * DD + col];
        a0.x += v0.x; a0.y += v0.y; a0.z += v0.z; a0.w += v0.w;
      }
      a0.x += a1.x; a0.y += a1.y; a0.z += a1.z; a0.w += a1.w;
      a2.x += a3.x; a2.y += a3.y; a2.z += a3.z; a2.w += a3.w;
      a0.x += a2.x; a0.y += a2.y; a0.z += a2.z; a0.w += a2.w;
      ushort h0, h1, h2, h3, l0, l1, l2, l3;
      bf16_split(a0.x, h0, l0);
      bf16_split(a0.y, h1, l1);
      bf16_split(a0.z, h2, l2);
      bf16_split(a0.w, h3, l3);
      int byte = (r * 256 + col * 2) ^ ((r & 7) << 4);
      *(ushort4*)((char*)Xhi + byte) = make_ushort4(h0, h1, h2, h3);
      *(ushort4*)((char*)Xlo + byte) = make_ushort4(l0, l1, l2, l3);
    }
  }
  __syncthreads();

  const int rowG = base + rb + l15;  // nf row for the global half of layer 1
  const f32x4 z = {0.f, 0.f, 0.f, 0.f};
  f32x4 acc[4];

  // ---- layer 1: k 0..127 from X (LDS), k 128..255 from nf (global) ----
#pragma unroll
  for (int ct = 0; ct < 4; ++ct) acc[ct] = z;
  lds_ksteps<8>(Xhi, Xlo, wt + WT1HI, wt + WT1LO, 0, rb, wc, lane, l15, lhi, acc);
#pragma unroll 2
  for (int kk = 0; kk < 4; ++kk)
    l1_step(nf, wt, kk + 4, kk * 32, rowG, wc, lane, lhi, acc);
  __syncthreads();  // all reads of X done before H1 overwrites it
  store_h(Xhi, Xlo, b1, rb, wc, l15, lhi, acc);
  __syncthreads();

  // ---- layer 2 ----
#pragma unroll
  for (int ct = 0; ct < 4; ++ct) acc[ct] = z;
  lds_ksteps<4>(Xhi, Xlo, wt + WT2HI, wt + WT2LO, 0, rb, wc, lane, l15, lhi, acc);
  __syncthreads();
  store_h(Xhi, Xlo, b2, rb, wc, l15, lhi, acc);
  __syncthreads();

  // ---- layer 3 ----
#pragma unroll
  for (int ct = 0; ct < 4; ++ct) acc[ct] = z;
  lds_ksteps<4>(Xhi, Xlo, wt + WT3HI, wt + WT3LO, 0, rb, wc, lane, l15, lhi, acc);
#pragma unroll
  for (int ct = 0; ct < 4; ++ct) {
    int col = wc * 64 + ct * 16 + l15;
    float bias = b3[col];
#pragma unroll
    for (int i = 0; i < 4; ++i) {
      int row = base + rb + lhi * 4 + i;
      out[row * DD + col] = acc[ct][i] + bias;
    }
  }
}

extern "C" void kernel_launch(void* const* d_in, const int* in_sizes, int n_in,
                              void* d_out, int out_size, void* d_ws, size_t ws_size,
                              hipStream_t stream) {
  const float* nf = (const float*)d_in[0];
  const int* src = (const int*)d_in[1];
  const int* dst = (const int*)d_in[2];
  const float* W1 = (const float*)d_in[3];
  const float* b1 = (const float*)d_in[4];
  const float* W2 = (const float*)d_in[5];
  const float* b2 = (const float*)d_in[6];
  const float* W3 = (const float*)d_in[7];
  const float* b3 = (const float*)d_in[8];
  float* out = (float*)d_out;

  int* wsi = (int*)d_ws;
  int* gcur = wsi + WS_GCUR;    // 98: bucket cursors / counts
  int* bbase = wsi + WS_BBASE;  // 98: exclusive bucket bases
  int* offs = wsi + WS_OFFS;    // 100001
  int* esrc = wsi + WS_ESRC;    // 1600000
  ushort* wt = (ushort*)wsi;    // 256KB weight tables in [0,100000) region

  // Scratch carved from `out`: coarse-bucket edge buffer (98 x 20480 x 4B = 8MB).
  // Dead after bucket_csr; fused_kernel later writes every row of out.
  unsigned* ebuf = (unsigned*)out;

  hipMemsetAsync(gcur, 0, NBUCK * sizeof(int), stream);
  bin1_kernel<<<BIN1_WGS, 256, 0, stream>>>(src, dst, gcur, ebuf);
  bscan_kernel<<<1, 128, 0, stream>>>(gcur, bbase, offs);
  bucket_csr_kernel<<<NBUCK, 1024, 0, stream>>>(ebuf, gcur, bbase, offs, esrc);
  wprep_kernel<<<256, 256, 0, stream>>>(W1, W2, W3, wt);
  fused_kernel<<<NBLK_MLP, 256, 0, stream>>>(nf, offs, esrc, wt, b1, b2, b3, out);
}

// Round 8
// 250.632 us; speedup vs baseline: 1.0156x; 1.0156x over previous
//
#include <hip/hip_runtime.h>

#define NNODES 100000
#define NEDGES 1600000
#define DD 128
#define BM 32
#define NBUCK 98                 // coarse buckets of 1024 nodes
#define NBLK_MLP (NNODES / BM)   // 3125 exactly (100000 = 3125*32)
#define CAP 32                   // bin1 LDS staging entries per bucket
#define CAPB 20480               // ebuf capacity per bucket (mean 16327)
#define BIN1_WGS 200
#define BIN1_EPW 8192            // edges per workgroup (8 rounds x 1024)

// ---------------- workspace layout (ints) ----------------
// [0,100000): weight tables (ushort view)
// [100000,100098): gcur | [100128,100226): bbase
// [100352,200353): offs | [201216,1801216): esrc
#define WS_GCUR 100000
#define WS_BBASE 100128
#define WS_OFFS 100352
#define WS_ESRC 201216

// ushort offsets inside the weight-table region (tile-packed)
#define WT1HI 0        // K=256: 8 c16 x 8 kk tiles, 1KB/tile
#define WT1LO 32768
#define WT2HI 65536    // K=128: 8 x 4 tiles
#define WT2LO 81920
#define WT3HI 98304
#define WT3LO 114688

typedef __attribute__((ext_vector_type(8))) short short8;  // 8 bf16
typedef __attribute__((ext_vector_type(4))) float f32x4;

// x ~= hi + lo, both bf16 (RNE). hi*whi + hi*wlo + lo*whi gives ~2^-16 rel err.
__device__ __forceinline__ void bf16_split(float x, ushort& hi, ushort& lo) {
  unsigned u = __float_as_uint(x);
  ushort h = (ushort)((u + 0x7FFFu + ((u >> 16) & 1u)) >> 16);
  float r = x - __uint_as_float(((unsigned)h) << 16);  // exact in fp32
  unsigned v = __float_as_uint(r);
  ushort l = (ushort)((v + 0x7FFFu + ((v >> 16) & 1u)) >> 16);
  hi = h;
  lo = l;
}

__device__ __forceinline__ void split8(const float4 v0, const float4 v1,
                                       short8& hi, short8& lo) {
  float x[8] = {v0.x, v0.y, v0.z, v0.w, v1.x, v1.y, v1.z, v1.w};
#pragma unroll
  for (int j = 0; j < 8; ++j) {
    ushort h, l;
    bf16_split(x[j], h, l);
    hi[j] = (short)h;
    lo[j] = (short)l;
  }
}

// ---------------- bin1: coarse-bucket scatter, LDS line-coalesced flush -------
__global__ __launch_bounds__(256) void bin1_kernel(const int* __restrict__ src,
                                                   const int* __restrict__ dst,
                                                   int* __restrict__ gcur,
                                                   unsigned* __restrict__ ebuf) {
  __shared__ unsigned stage[NBUCK][CAP];
  __shared__ int scnt[NBUCK];
  const int t = threadIdx.x;
  for (int i = t; i < NBUCK; i += 256) scnt[i] = 0;
  __syncthreads();
  const int e0 = blockIdx.x * BIN1_EPW;
  for (int r = 0; r < BIN1_EPW / 1024; ++r) {
    unsigned item[4];
    int buck[4];
    int pend[4];
#pragma unroll
    for (int j = 0; j < 4; ++j) {
      pend[j] = 0;
      int e = e0 + r * 1024 + j * 256 + t;
      if (e < NEDGES) {
        int d = dst[e];
        int s = src[e];
        buck[j] = d >> 10;
        item[j] = ((unsigned)(d & 1023) << 17) | (unsigned)s;
        int p = atomicAdd(&scnt[buck[j]], 1);
        if (p < CAP)
          stage[buck[j]][p] = item[j];
        else
          pend[j] = 1;
      }
    }
    int pendLeft;
    do {
      __syncthreads();
      if (t < NBUCK && scnt[t] >= CAP) {
        int base = t * CAPB + atomicAdd(&gcur[t], CAP);
        for (int q = 0; q < CAP; ++q) ebuf[base + q] = stage[t][q];
        scnt[t] = 0;
      }
      __syncthreads();
      int mypend = 0;
#pragma unroll
      for (int j = 0; j < 4; ++j) {
        if (pend[j]) {
          int p = atomicAdd(&scnt[buck[j]], 1);
          if (p < CAP) {
            stage[buck[j]][p] = item[j];
            pend[j] = 0;
          } else {
            mypend = 1;
          }
        }
      }
      pendLeft = __syncthreads_count(mypend);
    } while (pendLeft > 0);
  }
  __syncthreads();
  if (t < NBUCK) {
    int n = scnt[t];
    if (n > 0) {
      int base = t * CAPB + atomicAdd(&gcur[t], n);
      for (int q = 0; q < n; ++q) ebuf[base + q] = stage[t][q];
    }
  }
}

// ---------------- bscan: exclusive scan of 98 bucket counts ------------------
__global__ __launch_bounds__(128) void bscan_kernel(const int* __restrict__ gcur,
                                                    int* __restrict__ bbase,
                                                    int* __restrict__ offs) {
  __shared__ int s[128];
  const int t = threadIdx.x;
  int v = (t < NBUCK) ? gcur[t] : 0;
  s[t] = v;
  __syncthreads();
  for (int off = 1; off < 128; off <<= 1) {
    int u = (t >= off) ? s[t - off] : 0;
    __syncthreads();
    s[t] += u;
    __syncthreads();
  }
  if (t < NBUCK) bbase[t] = s[t] - v;
  if (t == NBUCK - 1) offs[NNODES] = s[t];
}

// ---------------- bucket_csr: LDS hist + scan + scatter ----------------------
__global__ __launch_bounds__(1024) void bucket_csr_kernel(const unsigned* __restrict__ ebuf,
                                                          const int* __restrict__ gcur,
                                                          const int* __restrict__ bbase,
                                                          int* __restrict__ offs,
                                                          int* __restrict__ esrc) {
  __shared__ int h[1024];
  __shared__ int cur[1024];
  const int t = threadIdx.x;
  const int c = blockIdx.x;
  const int n = gcur[c];
  const unsigned* eb = ebuf + c * CAPB;
  h[t] = 0;
  __syncthreads();
  for (int i = t; i < n; i += 1024) atomicAdd(&h[eb[i] >> 17], 1);
  __syncthreads();
  int v = h[t];
  for (int off = 1; off < 1024; off <<= 1) {
    int u = (t >= off) ? h[t - off] : 0;
    __syncthreads();
    h[t] += u;
    __syncthreads();
  }
  int excl = h[t] - v + bbase[c];
  int node = (c << 10) + t;
  if (node < NNODES) offs[node] = excl;
  cur[t] = excl;
  __syncthreads();
  for (int i = t; i < n; i += 1024) {
    unsigned e = eb[i];
    int p = atomicAdd(&cur[e >> 17], 1);
    esrc[p] = (int)(e & 0x1FFFFu);
  }
}

// ---------------- weight prep: fp32 -> split-bf16, tile-packed ----------------
__global__ __launch_bounds__(256) void wprep_kernel(const float* __restrict__ W1,
                                                    const float* __restrict__ W2,
                                                    const float* __restrict__ W3,
                                                    ushort* __restrict__ wt) {
  int tid = blockIdx.x * 256 + threadIdx.x;  // 65536 total
  const float* W;
  int dstHi, dstLo, k, col;
  if (tid < 32768) {  // layer 1, K=256: tiles = c16*8 + kk
    int j = tid & 7, l = (tid >> 3) & 63, tile = tid >> 9;
    int kk = tile & 7, c16 = tile >> 3;
    k = kk * 32 + (l >> 4) * 8 + j;
    col = c16 * 16 + (l & 15);
    W = W1;
    dstHi = WT1HI + tid;
    dstLo = WT1LO + tid;
  } else {  // layers 2/3, K=128: tiles = c16*4 + kk
    int t2 = tid - 32768;
    int which = t2 >> 14;
    int t1 = t2 & 16383;
    int j = t1 & 7, l = (t1 >> 3) & 63, tile = t1 >> 9;
    int kk = tile & 3, c16 = tile >> 2;
    k = kk * 32 + (l >> 4) * 8 + j;
    col = c16 * 16 + (l & 15);
    W = which ? W3 : W2;
    dstHi = (which ? WT3HI : WT2HI) + t1;
    dstLo = (which ? WT3LO : WT2LO) + t1;
  }
  ushort hi, lo;
  bf16_split(W[k * DD + col], hi, lo);
  wt[dstHi] = hi;
  wt[dstLo] = lo;
}

// ---------------- fused gather + MFMA MLP (BM=32, 16KB LDS) ----------------
// Frag maps (verified): A: lane l = A[row=l&15][k=(l>>4)*8+j];
// B: lane l = B[k=(l>>4)*8+j][col=l&15]; D: lane l reg i = [(l>>4)*4+i][l&15].

// 4 k-steps from swizzled LDS ([32][128] ushort, 256B row stride).
template <int KT>
__device__ __forceinline__ void lds_ksteps(const ushort* Hh, const ushort* Hl,
                                           const ushort* __restrict__ WhiT,
                                           const ushort* __restrict__ WloT,
                                           int tileOff, int rb, int wc, int lane,
                                           int l15, int lhi, f32x4 acc[4]) {
#pragma unroll 2
  for (int kk = 0; kk < 4; ++kk) {
    int row = rb + l15;
    int byte = (row * 256 + kk * 64 + lhi * 16) ^ ((row & 7) << 4);
    short8 ahi = *(const short8*)((const char*)Hh + byte);
    short8 alo = *(const short8*)((const char*)Hl + byte);
#pragma unroll
    for (int ct = 0; ct < 4; ++ct) {
      int tb = ((wc * 4 + ct) * KT + tileOff + kk) * 512 + lane * 8;
      short8 bhi = *(const short8*)&WhiT[tb];
      short8 blo = *(const short8*)&WloT[tb];
      acc[ct] = __builtin_amdgcn_mfma_f32_16x16x32_bf16(ahi, bhi, acc[ct], 0, 0, 0);
      acc[ct] = __builtin_amdgcn_mfma_f32_16x16x32_bf16(ahi, blo, acc[ct], 0, 0, 0);
      acc[ct] = __builtin_amdgcn_mfma_f32_16x16x32_bf16(alo, bhi, acc[ct], 0, 0, 0);
    }
  }
}

// one 32-k step with A from global memory (nf half of layer 1)
__device__ __forceinline__ void l1_step(const float* __restrict__ srcb,
                                        const ushort* __restrict__ wt,
                                        int kkTile, int kOff, int rowA,
                                        int wc, int lane, int lhi,
                                        f32x4 acc[4]) {
  const float* p = srcb + rowA * DD + kOff + lhi * 8;
  float4 v0 = *(const float4*)p;
  float4 v1 = *(const float4*)(p + 4);
  short8 ahi, alo;
  split8(v0, v1, ahi, alo);
#pragma unroll
  for (int ct = 0; ct < 4; ++ct) {
    int tb = ((wc * 4 + ct) * 8 + kkTile) * 512 + lane * 8;
    short8 bhi = *(const short8*)&wt[WT1HI + tb];
    short8 blo = *(const short8*)&wt[WT1LO + tb];
    acc[ct] = __builtin_amdgcn_mfma_f32_16x16x32_bf16(ahi, bhi, acc[ct], 0, 0, 0);
    acc[ct] = __builtin_amdgcn_mfma_f32_16x16x32_bf16(ahi, blo, acc[ct], 0, 0, 0);
    acc[ct] = __builtin_amdgcn_mfma_f32_16x16x32_bf16(alo, bhi, acc[ct], 0, 0, 0);
  }
}

// bias + ReLU + split-bf16 + swizzled LDS store
__device__ __forceinline__ void store_h(ushort* Hh, ushort* Hl,
                                        const float* __restrict__ b,
                                        int rb, int wc, int l15, int lhi,
                                        f32x4 acc[4]) {
#pragma unroll
  for (int ct = 0; ct < 4; ++ct) {
    int col = wc * 64 + ct * 16 + l15;
    float bias = b[col];
#pragma unroll
    for (int i = 0; i < 4; ++i) {
      int row = rb + lhi * 4 + i;
      float v = fmaxf(acc[ct][i] + bias, 0.f);
      ushort h, l;
      bf16_split(v, h, l);
      int byte = (row * 256 + col * 2) ^ ((row & 7) << 4);
      *(ushort*)((char*)Hh + byte) = h;
      *(ushort*)((char*)Hl + byte) = l;
    }
  }
}

__global__ __launch_bounds__(256, 8) void fused_kernel(const float* __restrict__ nf,
                                                       const int* __restrict__ offs,
                                                       const int* __restrict__ esrc,
                                                       const ushort* __restrict__ wt,
                                                       const float* __restrict__ b1,
                                                       const float* __restrict__ b2,
                                                       const float* __restrict__ b3,
                                                       float* __restrict__ out) {
  // X (agg, split-bf16, swizzled) [32][128] hi/lo = 16KB.
  // H1 and H2 reuse the same region (barrier-separated).
  __shared__ ushort smem[8192];
  __shared__ int nextRow;
  ushort* Xhi = smem;
  ushort* Xlo = smem + 4096;

  const int t = threadIdx.x;
  const int lane = t & 63;
  const int w = t >> 6;
  const int rb = (w & 1) * 16;   // wave row base within block
  const int wc = w >> 1;         // wave 64-col half
  const int l15 = lane & 15;
  const int lhi = lane >> 4;
  const int base = blockIdx.x * BM;  // exact: 100000 = 3125*32

  if (t == 0) nextRow = 0;
  __syncthreads();

  // ---- phase 1: gather-aggregate this block's 32 nodes into X ----
  // Dynamic row assignment (LDS work counter) kills per-group degree skew;
  // esrc prefetch pipeline breaks the index->feature dependency chain.
  {
    const int l32 = t & 31;
    const int col = l32 << 2;    // 4 floats per lane
    for (;;) {
      int r;
      if (l32 == 0) r = atomicAdd(&nextRow, 1);
      r = __shfl(r, 0, 32);
      if (r >= BM) break;
      const int node = base + r;
      float4 a0 = make_float4(0.f, 0.f, 0.f, 0.f);
      float4 a1 = make_float4(0.f, 0.f, 0.f, 0.f);
      float4 a2 = make_float4(0.f, 0.f, 0.f, 0.f);
      float4 a3 = make_float4(0.f, 0.f, 0.f, 0.f);
      const int beg = offs[node];
      const int end = offs[node + 1];
      int i = beg;
      int s0, s1, s2, s3;
      const bool have4 = (i + 3 < end);
      if (have4) {
        s0 = esrc[i]; s1 = esrc[i + 1]; s2 = esrc[i + 2]; s3 = esrc[i + 3];
      }
      for (; i + 7 < end; i += 4) {
        int n0 = esrc[i + 4], n1 = esrc[i + 5], n2 = esrc[i + 6], n3 = esrc[i + 7];
        float4 v0 = *(const float4*)&nf[s0 * DD + col];
        float4 v1 = *(const float4*)&nf[s1 * DD + col];
        float4 v2 = *(const float4*)&nf[s2 * DD + col];
        float4 v3 = *(const float4*)&nf[s3 * DD + col];
        a0.x += v0.x; a0.y += v0.y; a0.z += v0.z; a0.w += v0.w;
        a1.x += v1.x; a1.y += v1.y; a1.z += v1.z; a1.w += v1.w;
        a2.x += v2.x; a2.y += v2.y; a2.z += v2.z; a2.w += v2.w;
        a3.x += v3.x; a3.y += v3.y; a3.z += v3.z; a3.w += v3.w;
        s0 = n0; s1 = n1; s2 = n2; s3 = n3;
      }
      if (have4) {  // last complete 4-batch (indices already in s0..s3)
        float4 v0 = *(const float4*)&nf[s0 * DD + col];
        float4 v1 = *(const float4*)&nf[s1 * DD + col];
        float4 v2 = *(const float4*)&nf[s2 * DD + col];
        float4 v3 = *(const float4*)&nf[s3 * DD + col];
        a0.x += v0.x; a0.y += v0.y; a0.z += v0.z; a0.w += v0.w;
        a1.x += v1.x; a1.y += v1.y; a1.z += v1.z; a1.w += v1.w;
        a2.x += v2.x; a2.y += v2.y; a2.z += v2.z; a2.w += v2.w;
        a3.x += v3.x; a3.y += v3.y; a3.z += v3.z; a3.w += v3.w;
        i += 4;
      }
      for (; i < end; ++i) {
        int s = esrc[i];
        float4 v0 = *(const float4*)&nf[s * DD + col];
        a0.x += v0.x; a0.y += v0.y; a0.z += v0.z; a0.w += v0.w;
      }
      a0.x += a1.x; a0.y += a1.y; a0.z += a1.z; a0.w += a1.w;
      a2.x += a3.x; a2.y += a3.y; a2.z += a3.z; a2.w += a3.w;
      a0.x += a2.x; a0.y += a2.y; a0.z += a2.z; a0.w += a2.w;
      ushort h0, h1, h2, h3, l0, l1, l2, l3;
      bf16_split(a0.x, h0, l0);
      bf16_split(a0.y, h1, l1);
      bf16_split(a0.z, h2, l2);
      bf16_split(a0.w, h3, l3);
      int byte = (r * 256 + col * 2) ^ ((r & 7) << 4);
      *(ushort4*)((char*)Xhi + byte) = make_ushort4(h0, h1, h2, h3);
      *(ushort4*)((char*)Xlo + byte) = make_ushort4(l0, l1, l2, l3);
    }
  }
  __syncthreads();

  const int rowG = base + rb + l15;  // nf row for the global half of layer 1
  const f32x4 z = {0.f, 0.f, 0.f, 0.f};
  f32x4 acc[4];

  // ---- layer 1: k 0..127 from X (LDS), k 128..255 from nf (global) ----
#pragma unroll
  for (int ct = 0; ct < 4; ++ct) acc[ct] = z;
  lds_ksteps<8>(Xhi, Xlo, wt + WT1HI, wt + WT1LO, 0, rb, wc, lane, l15, lhi, acc);
#pragma unroll 2
  for (int kk = 0; kk < 4; ++kk)
    l1_step(nf, wt, kk + 4, kk * 32, rowG, wc, lane, lhi, acc);
  __syncthreads();  // all reads of X done before H1 overwrites it
  store_h(Xhi, Xlo, b1, rb, wc, l15, lhi, acc);
  __syncthreads();

  // ---- layer 2 ----
#pragma unroll
  for (int ct = 0; ct < 4; ++ct) acc[ct] = z;
  lds_ksteps<4>(Xhi, Xlo, wt + WT2HI, wt + WT2LO, 0, rb, wc, lane, l15, lhi, acc);
  __syncthreads();
  store_h(Xhi, Xlo, b2, rb, wc, l15, lhi, acc);
  __syncthreads();

  // ---- layer 3 ----
#pragma unroll
  for (int ct = 0; ct < 4; ++ct) acc[ct] = z;
  lds_ksteps<4>(Xhi, Xlo, wt + WT3HI, wt + WT3LO, 0, rb, wc, lane, l15, lhi, acc);
#pragma unroll
  for (int ct = 0; ct < 4; ++ct) {
    int col = wc * 64 + ct * 16 + l15;
    float bias = b3[col];
#pragma unroll
    for (int i = 0; i < 4; ++i) {
      int row = base + rb + lhi * 4 + i;
      out[row * DD + col] = acc[ct][i] + bias;
    }
  }
}

extern "C" void kernel_launch(void* const* d_in, const int* in_sizes, int n_in,
                              void* d_out, int out_size, void* d_ws, size_t ws_size,
                              hipStream_t stream) {
  const float* nf = (const float*)d_in[0];
  const int* src = (const int*)d_in[1];
  const int* dst = (const int*)d_in[2];
  const float* W1 = (const float*)d_in[3];
  const float* b1 = (const float*)d_in[4];
  const float* W2 = (const float*)d_in[5];
  const float* b2 = (const float*)d_in[6];
  const float* W3 = (const float*)d_in[7];
  const float* b3 = (const float*)d_in[8];
  float* out = (float*)d_out;

  int* wsi = (int*)d_ws;
  int* gcur = wsi + WS_GCUR;    // 98: bucket cursors / counts
  int* bbase = wsi + WS_BBASE;  // 98: exclusive bucket bases
  int* offs = wsi + WS_OFFS;    // 100001
  int* esrc = wsi + WS_ESRC;    // 1600000
  ushort* wt = (ushort*)wsi;    // 256KB weight tables in [0,100000) region

  // Scratch carved from `out`: coarse-bucket edge buffer (98 x 20480 x 4B = 8MB).
  // Dead after bucket_csr; fused_kernel later writes every row of out.
  unsigned* ebuf = (unsigned*)out;

  hipMemsetAsync(gcur, 0, NBUCK * sizeof(int), stream);
  bin1_kernel<<<BIN1_WGS, 256, 0, stream>>>(src, dst, gcur, ebuf);
  bscan_kernel<<<1, 128, 0, stream>>>(gcur, bbase, offs);
  bucket_csr_kernel<<<NBUCK, 1024, 0, stream>>>(ebuf, gcur, bbase, offs, esrc);
  wprep_kernel<<<256, 256, 0, stream>>>(W1, W2, W3, wt);
  fused_kernel<<<NBLK_MLP, 256, 0, stream>>>(nf, offs, esrc, wt, b1, b2, b3, out);
}

// Round 9
// 239.960 us; speedup vs baseline: 1.0608x; 1.0445x over previous
//
#include <hip/hip_runtime.h>

#define NNODES 100000
#define NEDGES 1600000
#define DD 128
#define BM 64
#define NBUCK 98                           // coarse buckets of 1024 nodes
#define NBLK_MLP ((NNODES + BM - 1) / BM)  // 1563 (last block: 32 valid rows)
#define CAP 32                             // bin1 LDS staging entries per bucket
#define CAPB 20480                         // ebuf capacity per bucket (mean 16327)
#define BIN1_WGS 391
#define BIN1_EPW 4096                      // edges per workgroup (4 rounds x 1024)

// ---------------- workspace layout (ints) ----------------
// [0,100000): weight tables (ushort view)
// [100000,100098): gcur | [100128,100226): bbase
// [100352,200353): offs | [201216,1801216): esrc
#define WS_GCUR 100000
#define WS_BBASE 100128
#define WS_OFFS 100352
#define WS_ESRC 201216

// ushort offsets inside the weight-table region (tile-packed)
#define WT1HI 0        // K=256: 8 c16 x 8 kk tiles, 1KB/tile
#define WT1LO 32768
#define WT2HI 65536    // K=128: 8 x 4 tiles
#define WT2LO 81920
#define WT3HI 98304
#define WT3LO 114688

typedef __attribute__((ext_vector_type(8))) short short8;  // 8 bf16
typedef __attribute__((ext_vector_type(4))) float f32x4;

// x ~= hi + lo, both bf16 (RNE). hi*whi + hi*wlo + lo*whi gives ~2^-16 rel err.
__device__ __forceinline__ void bf16_split(float x, ushort& hi, ushort& lo) {
  unsigned u = __float_as_uint(x);
  ushort h = (ushort)((u + 0x7FFFu + ((u >> 16) & 1u)) >> 16);
  float r = x - __uint_as_float(((unsigned)h) << 16);  // exact in fp32
  unsigned v = __float_as_uint(r);
  ushort l = (ushort)((v + 0x7FFFu + ((v >> 16) & 1u)) >> 16);
  hi = h;
  lo = l;
}

__device__ __forceinline__ void split8(const float4 v0, const float4 v1,
                                       short8& hi, short8& lo) {
  float x[8] = {v0.x, v0.y, v0.z, v0.w, v1.x, v1.y, v1.z, v1.w};
#pragma unroll
  for (int j = 0; j < 8; ++j) {
    ushort h, l;
    bf16_split(x[j], h, l);
    hi[j] = (short)h;
    lo[j] = (short)l;
  }
}

// ---------------- bin1: coarse-bucket scatter, LDS line-coalesced flush -------
__global__ __launch_bounds__(256) void bin1_kernel(const int* __restrict__ src,
                                                   const int* __restrict__ dst,
                                                   int* __restrict__ gcur,
                                                   unsigned* __restrict__ ebuf) {
  __shared__ unsigned stage[NBUCK][CAP];
  __shared__ int scnt[NBUCK];
  const int t = threadIdx.x;
  for (int i = t; i < NBUCK; i += 256) scnt[i] = 0;
  __syncthreads();
  const int e0 = blockIdx.x * BIN1_EPW;
  for (int r = 0; r < BIN1_EPW / 1024; ++r) {
    unsigned item[4];
    int buck[4];
    int pend[4];
#pragma unroll
    for (int j = 0; j < 4; ++j) {
      pend[j] = 0;
      int e = e0 + r * 1024 + j * 256 + t;
      if (e < NEDGES) {
        int d = dst[e];
        int s = src[e];
        buck[j] = d >> 10;
        item[j] = ((unsigned)(d & 1023) << 17) | (unsigned)s;
        int p = atomicAdd(&scnt[buck[j]], 1);
        if (p < CAP)
          stage[buck[j]][p] = item[j];
        else
          pend[j] = 1;
      }
    }
    int pendLeft;
    do {
      __syncthreads();
      if (t < NBUCK && scnt[t] >= CAP) {
        int base = t * CAPB + atomicAdd(&gcur[t], CAP);
        for (int q = 0; q < CAP; ++q) ebuf[base + q] = stage[t][q];
        scnt[t] = 0;
      }
      __syncthreads();
      int mypend = 0;
#pragma unroll
      for (int j = 0; j < 4; ++j) {
        if (pend[j]) {
          int p = atomicAdd(&scnt[buck[j]], 1);
          if (p < CAP) {
            stage[buck[j]][p] = item[j];
            pend[j] = 0;
          } else {
            mypend = 1;
          }
        }
      }
      pendLeft = __syncthreads_count(mypend);
    } while (pendLeft > 0);
  }
  __syncthreads();
  if (t < NBUCK) {
    int n = scnt[t];
    if (n > 0) {
      int base = t * CAPB + atomicAdd(&gcur[t], n);
      for (int q = 0; q < n; ++q) ebuf[base + q] = stage[t][q];
    }
  }
}

// ---------------- bscan: exclusive scan of 98 bucket counts ------------------
__global__ __launch_bounds__(128) void bscan_kernel(const int* __restrict__ gcur,
                                                    int* __restrict__ bbase,
                                                    int* __restrict__ offs) {
  __shared__ int s[128];
  const int t = threadIdx.x;
  int v = (t < NBUCK) ? gcur[t] : 0;
  s[t] = v;
  __syncthreads();
  for (int off = 1; off < 128; off <<= 1) {
    int u = (t >= off) ? s[t - off] : 0;
    __syncthreads();
    s[t] += u;
    __syncthreads();
  }
  if (t < NBUCK) bbase[t] = s[t] - v;
  if (t == NBUCK - 1) offs[NNODES] = s[t];
}

// ---------------- bucket_csr: LDS hist + scan + scatter ----------------------
__global__ __launch_bounds__(1024) void bucket_csr_kernel(const unsigned* __restrict__ ebuf,
                                                          const int* __restrict__ gcur,
                                                          const int* __restrict__ bbase,
                                                          int* __restrict__ offs,
                                                          int* __restrict__ esrc) {
  __shared__ int h[1024];
  __shared__ int cur[1024];
  const int t = threadIdx.x;
  const int c = blockIdx.x;
  const int n = gcur[c];
  const unsigned* eb = ebuf + c * CAPB;
  h[t] = 0;
  __syncthreads();
  for (int i = t; i < n; i += 1024) atomicAdd(&h[eb[i] >> 17], 1);
  __syncthreads();
  int v = h[t];
  for (int off = 1; off < 1024; off <<= 1) {
    int u = (t >= off) ? h[t - off] : 0;
    __syncthreads();
    h[t] += u;
    __syncthreads();
  }
  int excl = h[t] - v + bbase[c];
  int node = (c << 10) + t;
  if (node < NNODES) offs[node] = excl;
  cur[t] = excl;
  __syncthreads();
  for (int i = t; i < n; i += 1024) {
    unsigned e = eb[i];
    int p = atomicAdd(&cur[e >> 17], 1);
    esrc[p] = (int)(e & 0x1FFFFu);
  }
}

// ---------------- weight prep: fp32 -> split-bf16, tile-packed ----------------
__global__ __launch_bounds__(256) void wprep_kernel(const float* __restrict__ W1,
                                                    const float* __restrict__ W2,
                                                    const float* __restrict__ W3,
                                                    ushort* __restrict__ wt) {
  int tid = blockIdx.x * 256 + threadIdx.x;  // 65536 total
  const float* W;
  int dstHi, dstLo, k, col;
  if (tid < 32768) {  // layer 1, K=256: tiles = c16*8 + kk
    int j = tid & 7, l = (tid >> 3) & 63, tile = tid >> 9;
    int kk = tile & 7, c16 = tile >> 3;
    k = kk * 32 + (l >> 4) * 8 + j;
    col = c16 * 16 + (l & 15);
    W = W1;
    dstHi = WT1HI + tid;
    dstLo = WT1LO + tid;
  } else {  // layers 2/3, K=128: tiles = c16*4 + kk
    int t2 = tid - 32768;
    int which = t2 >> 14;
    int t1 = t2 & 16383;
    int j = t1 & 7, l = (t1 >> 3) & 63, tile = t1 >> 9;
    int kk = tile & 3, c16 = tile >> 2;
    k = kk * 32 + (l >> 4) * 8 + j;
    col = c16 * 16 + (l & 15);
    W = which ? W3 : W2;
    dstHi = (which ? WT3HI : WT2HI) + t1;
    dstLo = (which ? WT3LO : WT2LO) + t1;
  }
  ushort hi, lo;
  bf16_split(W[k * DD + col], hi, lo);
  wt[dstHi] = hi;
  wt[dstLo] = lo;
}

// ---------------- fused gather + MFMA MLP (BM=64, col-split waves) ----------
// Frag maps (verified): A: lane l = A[row=l&15][k=(l>>4)*8+j];
// B: lane l = B[k=(l>>4)*8+j][col=l&15]; D: lane l reg i = [(l>>4)*4+i][l&15].
// Wave w owns ALL 64 rows x cols [w*32, w*32+32) -> cts {2w, 2w+1}; per-block
// B-table is read exactly once (4 waves x 2 disjoint cts) = 256KB/block.

// 4 k-steps from swizzled LDS ([64][128] ushort, 256B row stride).
template <int KT>
__device__ __forceinline__ void lds_ksteps(const ushort* Hh, const ushort* Hl,
                                           const ushort* __restrict__ WhiT,
                                           const ushort* __restrict__ WloT,
                                           int tileOff, int wc2, int lane,
                                           int l15, int lhi, f32x4 acc[4][2]) {
#pragma unroll 2
  for (int kk = 0; kk < 4; ++kk) {
    short8 bhi[2], blo[2];
#pragma unroll
    for (int ct = 0; ct < 2; ++ct) {
      int tb = ((wc2 + ct) * KT + tileOff + kk) * 512 + lane * 8;
      bhi[ct] = *(const short8*)&WhiT[tb];
      blo[ct] = *(const short8*)&WloT[tb];
    }
#pragma unroll
    for (int rt = 0; rt < 4; ++rt) {
      int row = rt * 16 + l15;
      int byte = (row * 256 + kk * 64 + lhi * 16) ^ ((row & 7) << 4);
      short8 ahi = *(const short8*)((const char*)Hh + byte);
      short8 alo = *(const short8*)((const char*)Hl + byte);
#pragma unroll
      for (int ct = 0; ct < 2; ++ct) {
        acc[rt][ct] = __builtin_amdgcn_mfma_f32_16x16x32_bf16(ahi, bhi[ct], acc[rt][ct], 0, 0, 0);
        acc[rt][ct] = __builtin_amdgcn_mfma_f32_16x16x32_bf16(ahi, blo[ct], acc[rt][ct], 0, 0, 0);
        acc[rt][ct] = __builtin_amdgcn_mfma_f32_16x16x32_bf16(alo, bhi[ct], acc[rt][ct], 0, 0, 0);
      }
    }
  }
}

// one 32-k step with A from global memory (nf half of layer 1)
__device__ __forceinline__ void l1_step(const float* __restrict__ srcb,
                                        const ushort* __restrict__ wt,
                                        int kkTile, int kOff, const int rowA[4],
                                        int wc2, int lane, int lhi,
                                        f32x4 acc[4][2]) {
  short8 bhi[2], blo[2];
#pragma unroll
  for (int ct = 0; ct < 2; ++ct) {
    int tb = ((wc2 + ct) * 8 + kkTile) * 512 + lane * 8;
    bhi[ct] = *(const short8*)&wt[WT1HI + tb];
    blo[ct] = *(const short8*)&wt[WT1LO + tb];
  }
#pragma unroll
  for (int rt = 0; rt < 4; ++rt) {
    const float* p = srcb + rowA[rt] * DD + kOff + lhi * 8;
    float4 v0 = *(const float4*)p;
    float4 v1 = *(const float4*)(p + 4);
    short8 ahi, alo;
    split8(v0, v1, ahi, alo);
#pragma unroll
    for (int ct = 0; ct < 2; ++ct) {
      acc[rt][ct] = __builtin_amdgcn_mfma_f32_16x16x32_bf16(ahi, bhi[ct], acc[rt][ct], 0, 0, 0);
      acc[rt][ct] = __builtin_amdgcn_mfma_f32_16x16x32_bf16(ahi, blo[ct], acc[rt][ct], 0, 0, 0);
      acc[rt][ct] = __builtin_amdgcn_mfma_f32_16x16x32_bf16(alo, bhi[ct], acc[rt][ct], 0, 0, 0);
    }
  }
}

// bias + ReLU + split-bf16 + swizzled LDS store
__device__ __forceinline__ void store_h(ushort* Hh, ushort* Hl,
                                        const float* __restrict__ b,
                                        int wc2, int l15, int lhi,
                                        f32x4 acc[4][2]) {
#pragma unroll
  for (int rt = 0; rt < 4; ++rt) {
#pragma unroll
    for (int ct = 0; ct < 2; ++ct) {
      int col = (wc2 + ct) * 16 + l15;
      float bias = b[col];
#pragma unroll
      for (int i = 0; i < 4; ++i) {
        int row = rt * 16 + lhi * 4 + i;
        float v = fmaxf(acc[rt][ct][i] + bias, 0.f);
        ushort h, l;
        bf16_split(v, h, l);
        int byte = (row * 256 + col * 2) ^ ((row & 7) << 4);
        *(ushort*)((char*)Hh + byte) = h;
        *(ushort*)((char*)Hl + byte) = l;
      }
    }
  }
}

__global__ __launch_bounds__(256, 5) void fused_kernel(const float* __restrict__ nf,
                                                       const int* __restrict__ offs,
                                                       const int* __restrict__ esrc,
                                                       const ushort* __restrict__ wt,
                                                       const float* __restrict__ b1,
                                                       const float* __restrict__ b2,
                                                       const float* __restrict__ b3,
                                                       float* __restrict__ out) {
  // X (agg, split-bf16, swizzled) [64][128] hi/lo = 32KB exactly.
  // H1 and H2 reuse the same region (barrier-separated).
  __shared__ ushort smem[16384];
  ushort* Xhi = smem;
  ushort* Xlo = smem + 8192;

  const int t = threadIdx.x;
  const int lane = t & 63;
  const int w = t >> 6;
  const int wc2 = w * 2;  // this wave's first col-tile (cols [w*32, w*32+32))
  const int l15 = lane & 15;
  const int lhi = lane >> 4;
  const int base = blockIdx.x * BM;

  // ---- phase 1: gather-aggregate this block's 64 nodes into X ----
  // Static groups (8 groups x 32 lanes, 8 rows each) + esrc prefetch pipeline.
  {
    const int g = t >> 5;
    const int l32 = t & 31;
    const int col = l32 << 2;  // 4 floats per lane
    for (int j = 0; j < 8; ++j) {
      const int r = g * 8 + j;  // block-local row
      const int node = base + r;
      if (node >= NNODES) break;  // tail block: rows >= valid stay stale (row-local, never stored)
      float4 a0 = make_float4(0.f, 0.f, 0.f, 0.f);
      float4 a1 = make_float4(0.f, 0.f, 0.f, 0.f);
      float4 a2 = make_float4(0.f, 0.f, 0.f, 0.f);
      float4 a3 = make_float4(0.f, 0.f, 0.f, 0.f);
      const int beg = offs[node];
      const int end = offs[node + 1];
      int i = beg;
      int s0, s1, s2, s3;
      const bool have4 = (i + 3 < end);
      if (have4) {
        s0 = esrc[i]; s1 = esrc[i + 1]; s2 = esrc[i + 2]; s3 = esrc[i + 3];
      }
      for (; i + 7 < end; i += 4) {
        int n0 = esrc[i + 4], n1 = esrc[i + 5], n2 = esrc[i + 6], n3 = esrc[i + 7];
        float4 v0 = *(const float4*)&nf[s0 * DD + col];
        float4 v1 = *(const float4*)&nf[s1 * DD + col];
        float4 v2 = *(const float4*)&nf[s2 * DD + col];
        float4 v3 = *(const float4*)&nf[s3 * DD + col];
        a0.x += v0.x; a0.y += v0.y; a0.z += v0.z; a0.w += v0.w;
        a1.x += v1.x; a1.y += v1.y; a1.z += v1.z; a1.w += v1.w;
        a2.x += v2.x; a2.y += v2.y; a2.z += v2.z; a2.w += v2.w;
        a3.x += v3.x; a3.y += v3.y; a3.z += v3.z; a3.w += v3.w;
        s0 = n0; s1 = n1; s2 = n2; s3 = n3;
      }
      if (have4) {  // last complete 4-batch (indices already in s0..s3)
        float4 v0 = *(const float4*)&nf[s0 * DD + col];
        float4 v1 = *(const float4*)&nf[s1 * DD + col];
        float4 v2 = *(const float4*)&nf[s2 * DD + col];
        float4 v3 = *(const float4*)&nf[s3 * DD + col];
        a0.x += v0.x; a0.y += v0.y; a0.z += v0.z; a0.w += v0.w;
        a1.x += v1.x; a1.y += v1.y; a1.z += v1.z; a1.w += v1.w;
        a2.x += v2.x; a2.y += v2.y; a2.z += v2.z; a2.w += v2.w;
        a3.x += v3.x; a3.y += v3.y; a3.z += v3.z; a3.w += v3.w;
        i += 4;
      }
      for (; i < end; ++i) {
        int s = esrc[i];
        float4 v0 = *(const float4*)&nf[s * DD + col];
        a0.x += v0.x; a0.y += v0.y; a0.z += v0.z; a0.w += v0.w;
      }
      a0.x += a1.x; a0.y += a1.y; a0.z += a1.z; a0.w += a1.w;
      a2.x += a3.x; a2.y += a3.y; a2.z += a3.z; a2.w += a3.w;
      a0.x += a2.x; a0.y += a2.y; a0.z += a2.z; a0.w += a2.w;
      ushort h0, h1, h2, h3, l0, l1, l2, l3;
      bf16_split(a0.x, h0, l0);
      bf16_split(a0.y, h1, l1);
      bf16_split(a0.z, h2, l2);
      bf16_split(a0.w, h3, l3);
      int byte = (r * 256 + col * 2) ^ ((r & 7) << 4);
      *(ushort4*)((char*)Xhi + byte) = make_ushort4(h0, h1, h2, h3);
      *(ushort4*)((char*)Xlo + byte) = make_ushort4(l0, l1, l2, l3);
    }
  }
  __syncthreads();

  // nf rows for the global half of layer 1 (clamped; stores are guarded)
  int rowA[4];
#pragma unroll
  for (int rt = 0; rt < 4; ++rt) rowA[rt] = min(base + rt * 16 + l15, NNODES - 1);

  const f32x4 z = {0.f, 0.f, 0.f, 0.f};
  f32x4 acc[4][2];

  // ---- layer 1: k 0..127 from X (LDS), k 128..255 from nf (global) ----
#pragma unroll
  for (int rt = 0; rt < 4; ++rt)
#pragma unroll
    for (int ct = 0; ct < 2; ++ct) acc[rt][ct] = z;
  lds_ksteps<8>(Xhi, Xlo, wt + WT1HI, wt + WT1LO, 0, wc2, lane, l15, lhi, acc);
#pragma unroll 2
  for (int kk = 0; kk < 4; ++kk)
    l1_step(nf, wt, kk + 4, kk * 32, rowA, wc2, lane, lhi, acc);
  __syncthreads();  // all reads of X done before H1 overwrites it
  store_h(Xhi, Xlo, b1, wc2, l15, lhi, acc);
  __syncthreads();

  // ---- layer 2 ----
#pragma unroll
  for (int rt = 0; rt < 4; ++rt)
#pragma unroll
    for (int ct = 0; ct < 2; ++ct) acc[rt][ct] = z;
  lds_ksteps<4>(Xhi, Xlo, wt + WT2HI, wt + WT2LO, 0, wc2, lane, l15, lhi, acc);
  __syncthreads();
  store_h(Xhi, Xlo, b2, wc2, l15, lhi, acc);
  __syncthreads();

  // ---- layer 3 ----
#pragma unroll
  for (int rt = 0; rt < 4; ++rt)
#pragma unroll
    for (int ct = 0; ct < 2; ++ct) acc[rt][ct] = z;
  lds_ksteps<4>(Xhi, Xlo, wt + WT3HI, wt + WT3LO, 0, wc2, lane, l15, lhi, acc);
#pragma unroll
  for (int rt = 0; rt < 4; ++rt) {
#pragma unroll
    for (int ct = 0; ct < 2; ++ct) {
      int col = (wc2 + ct) * 16 + l15;
      float bias = b3[col];
#pragma unroll
      for (int i = 0; i < 4; ++i) {
        int row = base + rt * 16 + lhi * 4 + i;
        if (row < NNODES) out[row * DD + col] = acc[rt][ct][i] + bias;
      }
    }
  }
}

extern "C" void kernel_launch(void* const* d_in, const int* in_sizes, int n_in,
                              void* d_out, int out_size, void* d_ws, size_t ws_size,
                              hipStream_t stream) {
  const float* nf = (const float*)d_in[0];
  const int* src = (const int*)d_in[1];
  const int* dst = (const int*)d_in[2];
  const float* W1 = (const float*)d_in[3];
  const float* b1 = (const float*)d_in[4];
  const float* W2 = (const float*)d_in[5];
  const float* b2 = (const float*)d_in[6];
  const float* W3 = (const float*)d_in[7];
  const float* b3 = (const float*)d_in[8];
  float* out = (float*)d_out;

  int* wsi = (int*)d_ws;
  int* gcur = wsi + WS_GCUR;    // 98: bucket cursors / counts
  int* bbase = wsi + WS_BBASE;  // 98: exclusive bucket bases
  int* offs = wsi + WS_OFFS;    // 100001
  int* esrc = wsi + WS_ESRC;    // 1600000
  ushort* wt = (ushort*)wsi;    // 256KB weight tables in [0,100000) region

  // Scratch carved from `out`: coarse-bucket edge buffer (98 x 20480 x 4B = 8MB).
  // Dead after bucket_csr; fused_kernel later writes every row of out.
  unsigned* ebuf = (unsigned*)out;

  hipMemsetAsync(gcur, 0, NBUCK * sizeof(int), stream);
  bin1_kernel<<<BIN1_WGS, 256, 0, stream>>>(src, dst, gcur, ebuf);
  bscan_kernel<<<1, 128, 0, stream>>>(gcur, bbase, offs);
  bucket_csr_kernel<<<NBUCK, 1024, 0, stream>>>(ebuf, gcur, bbase, offs, esrc);
  wprep_kernel<<<256, 256, 0, stream>>>(W1, W2, W3, wt);
  fused_kernel<<<NBLK_MLP, 256, 0, stream>>>(nf, offs, esrc, wt, b1, b2, b3, out);
}